// Round 4
// baseline (231.857 us; speedup 1.0000x reference)
//
#include <hip/hip_runtime.h>

typedef _Float16 half_t;
typedef _Float16 h2 __attribute__((ext_vector_type(2)));
typedef unsigned int uint32;

#define K_ 100
#define F_ 128
#define E_ 200
#define NBLK 640u

#if defined(__has_builtin)
#if __has_builtin(__builtin_amdgcn_fdot2)
#define FDOT2(a,b,c) __builtin_amdgcn_fdot2((a),(b),(c),false)
#endif
#endif
#ifndef FDOT2
#define FDOT2(a,b,c) fmaf((float)(a).y,(float)(b).y, fmaf((float)(a).x,(float)(b).x,(c)))
#endif

__device__ __forceinline__ h2 bch2(uint32 u){ return __builtin_bit_cast(h2,u); }
__device__ __forceinline__ uint32 pkh2(float a, float b){
  h2 p; p.x=(half_t)a; p.y=(half_t)b; return __builtin_bit_cast(uint32,p);
}

// ws layout (uint words):
//  Rh[6400][100] @0 ; AR[6400] f32 @640000 ; XJ[64*50][128] @646400
#define RH_OFF  0
#define AR_WOFF 640000
#define XJ_WOFF 646400

// Grid barrier state — module globals (NOT in ws: ws is poisoned each iter).
// Generation-based: robust across graph replays / repeated launches.
__device__ unsigned gbar_cnt = 0;
__device__ unsigned gbar_gen = 0;

__device__ __forceinline__ void grid_barrier()
{
  __syncthreads();
  if (threadIdx.x == 0) {
    __threadfence();   // device-scope release of this block's ws writes
    unsigned g = __hip_atomic_load(&gbar_gen, __ATOMIC_RELAXED, __HIP_MEMORY_SCOPE_AGENT);
    unsigned a = __hip_atomic_fetch_add(&gbar_cnt, 1u, __ATOMIC_ACQ_REL, __HIP_MEMORY_SCOPE_AGENT);
    if (a == NBLK - 1u) {
      __hip_atomic_store(&gbar_cnt, 0u, __ATOMIC_RELAXED, __HIP_MEMORY_SCOPE_AGENT);
      __hip_atomic_fetch_add(&gbar_gen, 1u, __ATOMIC_RELEASE, __HIP_MEMORY_SCOPE_AGENT);
    } else {
      unsigned long long t0 = __builtin_amdgcn_s_memrealtime();
      while (__hip_atomic_load(&gbar_gen, __ATOMIC_ACQUIRE, __HIP_MEMORY_SCOPE_AGENT) == g) {
        __builtin_amdgcn_s_sleep(8);
        if (__builtin_amdgcn_s_memrealtime() - t0 > 100000000ull) break;  // ~1s bailout
      }
    }
    __threadfence();   // acquire side for subsequent reads
  }
  __syncthreads();
}

// one e-uint (2 e's): nonlinear term only (al/ar precomputed in proj phase)
#define STEP(lu, au, r0u, r1u, r2u, r3u)                                   \
  do {                                                                     \
    h2 a2 = bch2(au); h2 l2 = bch2(lu); h2 mm;                             \
    mm = __builtin_elementwise_min(l2 + bch2(r0u), z2); acc[0] = FDOT2(a2, mm, acc[0]); \
    mm = __builtin_elementwise_min(l2 + bch2(r1u), z2); acc[1] = FDOT2(a2, mm, acc[1]); \
    mm = __builtin_elementwise_min(l2 + bch2(r2u), z2); acc[2] = FDOT2(a2, mm, acc[2]); \
    mm = __builtin_elementwise_min(l2 + bch2(r3u), z2); acc[3] = FDOT2(a2, mm, acc[3]); \
  } while (0)

#define RPAD 104   // 104%32=8 -> within-instr max 2-way bank alias (free); %4==0 for uint4
#define LPAD 108   // 108%32=12 -> 2-way max; %4==0

// Single fused kernel. grid (10,64) x 256thr; 3 blocks/CU (LDS 52.4KB, VGPR<=170)
// so all 640 blocks are co-resident for the grid barrier.
// Phase P: projections (W read direct from global, per-wave coalesced),
//          L rows -> Lsh (block-local), R rows+XJ+AR -> ws, AL -> LDS.
// Barrier. Phase M: stage R, pair sweep, softmax, PV, sigmoid, out.
__global__ __launch_bounds__(256, 3) void k_fused(
    const float* __restrict__ x, const float* __restrict__ W,
    const float* __restrict__ bvec, const float* __restrict__ avec,
    const float* __restrict__ bias, uint32* __restrict__ ws,
    float* __restrict__ out)
{
  const int t  = threadIdx.x;
  const int ib = (int)blockIdx.x;        // 0..9
  const int b  = (int)blockIdx.y;        // 0..63
  const int i0 = ib * 10;
  const int r0 = b * K_ + i0;            // global row base (6400 rows total)

  __shared__ __align__(16) uint32 RshU[100 * RPAD];  // 41.6KB; proj-phase alias: xsh, red
  __shared__ __align__(16) uint32 Lsh[10 * LPAD];    //  4.3KB
  __shared__ __align__(16) uint32 Ash[100];
  __shared__ float  ALsh[12];
  __shared__ __align__(16) float attU[10 * K_];      // 4KB; aliases scratch (barrier-separated)
  __shared__ uint32 att2[10 * 50];
  __shared__ float  rowmax[10], rowinv[10];

  uint32* xsh = RshU;                    // [10][64] h2 f-pairs
  float*  red = (float*)(RshU + 640);    // [20][100] al/ar partials
  float*  scratch = attU;                // [256]

  // ================= Phase P: projection =================
  for (int u = t; u < 640; u += 256) {
    int row = u >> 6, f2 = u & 63;
    const float* xp = x + (size_t)(r0 + row) * F_ + 2 * f2;
    xsh[row * 64 + f2] = pkh2(xp[0], xp[1]);
  }
  if (t < 100) Ash[t] = pkh2(avec[2*t], avec[2*t+1]);
  __syncthreads();

  // XJ: pack (x[2jp][f], x[2jp+1][f]) for this block's 5 j-pairs
  for (int u = t; u < 640; u += 256) {
    int f = u & 127, lp = u >> 7;
    uint32 u0 = xsh[(2*lp)     * 64 + (f >> 1)];
    uint32 u1 = xsh[(2*lp + 1) * 64 + (f >> 1)];
    int sh = (f & 1) * 16;
    ws[XJ_WOFF + (size_t)(b*50 + ib*5 + lp) * 128 + f] =
        ((u0 >> sh) & 0xffffu) | (((u1 >> sh) & 0xffffu) << 16);
  }

  if (t < 200) {
    const bool isR = (t >= 100);
    const int e2 = isR ? (t - 100) : t;          // output uint index within row
    const float* Wp = W + (size_t)(isR ? 128 : 0) * E_ + 2 * e2;

    float acc0[10], acc1[10];
    #pragma unroll
    for (int r = 0; r < 10; ++r) { acc0[r] = 0.f; acc1[r] = 0.f; }

    #pragma unroll
    for (int q = 0; q < 16; ++q) {
      uint32 w0u[4], w1u[4];
      #pragma unroll
      for (int fp = 0; fp < 4; ++fp) {           // per-wave: contiguous 512B row reads
        const float* p0 = Wp + (size_t)(8*q + 2*fp) * E_;
        float2 Av = *(const float2*)p0;
        float2 Bv = *(const float2*)(p0 + E_);
        w0u[fp] = pkh2(Av.x, Bv.x);
        w1u[fp] = pkh2(Av.y, Bv.y);
      }
      #pragma unroll
      for (int r = 0; r < 10; ++r) {
        uint4 xq = *(const uint4*)(xsh + r * 64 + 4 * q);   // uniform -> broadcast
        acc0[r] = FDOT2(bch2(xq.x), bch2(w0u[0]), acc0[r]);
        acc0[r] = FDOT2(bch2(xq.y), bch2(w0u[1]), acc0[r]);
        acc0[r] = FDOT2(bch2(xq.z), bch2(w0u[2]), acc0[r]);
        acc0[r] = FDOT2(bch2(xq.w), bch2(w0u[3]), acc0[r]);
        acc1[r] = FDOT2(bch2(xq.x), bch2(w1u[0]), acc1[r]);
        acc1[r] = FDOT2(bch2(xq.y), bch2(w1u[1]), acc1[r]);
        acc1[r] = FDOT2(bch2(xq.z), bch2(w1u[2]), acc1[r]);
        acc1[r] = FDOT2(bch2(xq.w), bch2(w1u[3]), acc1[r]);
      }
    }
    if (isR) {
      float b0 = bvec[2 * e2], b1 = bvec[2 * e2 + 1];
      #pragma unroll
      for (int r = 0; r < 10; ++r) { acc0[r] += b0; acc1[r] += b1; }
    }
    h2 a2 = bch2(Ash[e2]);
    #pragma unroll
    for (int r = 0; r < 10; ++r) {
      uint32 pr = pkh2(acc0[r], acc1[r]);
      if (isR) ws[RH_OFF + (size_t)(r0 + r) * 100 + e2] = pr;   // R -> ws (all blocks of b)
      else     Lsh[r * LPAD + e2] = pr;                          // L stays local
      red[(isR ? 10 : 0) * 100 + r * 100 + e2] = FDOT2(a2, bch2(pr), 0.f);
    }
  }
  __syncthreads();

  // AL[row]=a·L_row (local); AR[row]=a·(R_row+b) -> ws
  if (t < 20) {
    float s = 0.f;
    const float* rp = red + t * 100;
    for (int k = 0; k < 100; ++k) s += rp[k];
    if (t < 10) ALsh[t] = s;
    else       ((float*)ws)[AR_WOFF + r0 + (t - 10)] = s;
  }

  grid_barrier();

  // ================= Phase M: attention =================
  {
    const uint32* Rb = ws + RH_OFF + (size_t)b * K_ * 100;
    for (int u = t; u < 2500; u += 256) {            // 100 rows x 25 uint4
      int row = u / 25, c4 = (u % 25) * 4;
      *(uint4*)(&RshU[row * RPAD + c4]) = *(const uint4*)(Rb + (size_t)row * 100 + c4);
    }
  }
  __syncthreads();

  const bool act = (t < 250);
  const int ti = act ? (t % 10) : 0;
  const int tj = act ? (t / 10) : 0;

  float acc[4] = {0.f,0.f,0.f,0.f};
  h2 z2; z2.x = (half_t)0; z2.y = (half_t)0;

  if (act) {
    const uint32* Lp  = Lsh  + ti * LPAD;
    const uint32* Rp0 = RshU + tj * RPAD;
    const uint32* Rp1 = RshU + (tj + 25) * RPAD;
    const uint32* Rp2 = RshU + (tj + 50) * RPAD;
    const uint32* Rp3 = RshU + (tj + 75) * RPAD;
    #pragma unroll 5
    for (int q = 0; q < 25; ++q) {
      uint4 Lq  = *(const uint4*)(Lp  + 4*q);
      uint4 Aq  = *(const uint4*)(Ash + 4*q);
      uint4 R0q = *(const uint4*)(Rp0 + 4*q);
      uint4 R1q = *(const uint4*)(Rp1 + 4*q);
      uint4 R2q = *(const uint4*)(Rp2 + 4*q);
      uint4 R3q = *(const uint4*)(Rp3 + 4*q);
      STEP(Lq.x, Aq.x, R0q.x, R1q.x, R2q.x, R3q.x);
      STEP(Lq.y, Aq.y, R0q.y, R1q.y, R2q.y, R3q.y);
      STEP(Lq.z, Aq.z, R0q.z, R1q.z, R2q.z, R3q.z);
      STEP(Lq.w, Aq.w, R0q.w, R1q.w, R2q.w, R3q.w);
    }
  }

  float v[4];
  if (act) {
    const float* ARf = (const float*)ws + AR_WOFF;
    float al = ALsh[ti];
    #pragma unroll
    for (int s = 0; s < 4; ++s) {
      int j = tj + 25*s;
      float lv = al + ARf[b*K_ + j] + bias[(i0 + ti)*K_ + j] - 0.8f*acc[s];
      v[s] = fminf(fmaxf(lv, -30000.f), 30000.f);
    }
  }

  {
    float m = -3.0e38f;
    if (act) {
      #pragma unroll
      for (int s = 0; s < 4; ++s) m = fmaxf(m, v[s]);
    }
    scratch[t] = m;
    __syncthreads();
    if (t < 10) {
      float mm = scratch[t];
      for (int k = 1; k < 25; ++k) mm = fmaxf(mm, scratch[t + 10*k]);
      rowmax[t] = mm;
    }
    __syncthreads();
    float ssum = 0.f;
    if (act) {
      float m2 = rowmax[ti];
      #pragma unroll
      for (int s = 0; s < 4; ++s) ssum += __expf(v[s] - m2);
    }
    scratch[t] = ssum;
    __syncthreads();
    if (t < 10) {
      float s2 = 0.f;
      for (int k = 0; k < 25; ++k) s2 += scratch[t + 10*k];
      rowinv[t] = 1.f / s2;
    }
    __syncthreads();   // also separates scratch (alias) from att writes below
  }
  if (act) {
    float m = rowmax[ti], inv = rowinv[ti];
    #pragma unroll
    for (int s = 0; s < 4; ++s)
      attU[ti*K_ + tj + 25*s] = __expf(v[s] - m) * inv;
  }
  __syncthreads();
  for (int u = t; u < 500; u += 256) {
    int i = u / 50, jp = u - i*50;
    att2[i*50 + jp] = pkh2(attU[i*K_ + 2*jp], attU[i*K_ + 2*jp + 1]);
  }
  __syncthreads();

  {
    const int f = t & 127, ig = t >> 7;        // ig in {0,1}
    const uint32* XJ = ws + XJ_WOFF + (size_t)(b*50) * 128;
    float z[5];
    #pragma unroll
    for (int m = 0; m < 5; ++m) z[m] = 0.f;
    for (int jp = 0; jp < 50; ++jp) {
      h2 xv = bch2(XJ[jp*128 + f]);            // coalesced, pre-packed
      #pragma unroll
      for (int m = 0; m < 5; ++m) {
        h2 av = bch2(att2[(ig*5 + m)*50 + jp]);
        z[m] = FDOT2(av, xv, z[m]);
      }
    }
    #pragma unroll
    for (int m = 0; m < 5; ++m) {
      int i = ig*5 + m;
      out[(size_t)(b*K_ + i0 + i)*F_ + f] = 1.f / (1.f + __expf(-z[m]));
    }
  }
}

extern "C" void kernel_launch(void* const* d_in, const int* in_sizes, int n_in,
                              void* d_out, int out_size, void* d_ws, size_t ws_size,
                              hipStream_t stream)
{
  const float* x    = (const float*)d_in[0];   // (64,100,128) f32
  const float* W    = (const float*)d_in[1];   // (256,200) f32
  const float* bvec = (const float*)d_in[2];   // (200,) f32
  const float* avec = (const float*)d_in[3];   // (200,) f32
  const float* bias = (const float*)d_in[4];   // (100,100) f32
  float* out  = (float*)d_out;                 // (64,100,128) f32
  uint32* ws  = (uint32*)d_ws;                 // ~4.2 MB used

  k_fused<<<dim3(10, 64), dim3(256), 0, stream>>>(x, W, bvec, avec, bias, ws, out);
}

// Round 7
// 98.345 us; speedup vs baseline: 2.3576x; 2.3576x over previous
//
// v6-r7: identical semantics to R5/R6 submission; comment bump to bust any
// content-hash caching in the submission path after repeated broker failures.
#include <hip/hip_runtime.h>

typedef _Float16 half_t;
typedef _Float16 h2 __attribute__((ext_vector_type(2)));
typedef unsigned int uint32;

#define K_ 100
#define F_ 128
#define E_ 200

#if defined(__has_builtin)
#if __has_builtin(__builtin_amdgcn_fdot2)
#define FDOT2(a,b,c) __builtin_amdgcn_fdot2((a),(b),(c),false)
#endif
#endif
#ifndef FDOT2
#define FDOT2(a,b,c) fmaf((float)(a).y,(float)(b).y, fmaf((float)(a).x,(float)(b).x,(c)))
#endif

__device__ __forceinline__ h2 bch2(uint32 u){ return __builtin_bit_cast(h2,u); }
__device__ __forceinline__ uint32 pkh2(float a, float b){
  h2 p; p.x=(half_t)a; p.y=(half_t)b; return __builtin_bit_cast(uint32,p);
}

// ws layout (uint words):
//  Lh[6400][100] @0 ; Rh[6400][100] @640000 ; ah2[100] @1280000
//  AL[6400] f32 @1280128 ; AR[6400] f32 @1286528 ; XJ[64*50][128] @1292928
#define LH_OFF 0
#define RH_OFF 640000
#define AH_OFF 1280000
#define AL_OFF 1280128
#define AR_OFF 1286528
#define XJ_OFF 1292928

// K1: projection with W read DIRECT from global (k_wt merged away).
// Per-wave W reads are contiguous 512B row segments (lanes = consecutive
// e-columns), W (200KB) stays L2-hot. Packing order identical to old k_wt:
// w-pair = (W[f][e], W[f+1][e]) -> bit-identical FDOT2 operands.
// Also emits AL/AR row-dots and the XJ j-paired h2 repack of x.
__global__ __launch_bounds__(256) void k_proj(
    const float* __restrict__ x, const float* __restrict__ W,
    const float* __restrict__ bvec, const float* __restrict__ avec,
    uint32* __restrict__ ws)
{
  const int t  = threadIdx.x;
  const int r0 = (int)blockIdx.x * 10;

  __shared__ __align__(16) uint32 xsh[10 * 64];   // x rows, h2 f-pairs
  __shared__ float red[20][100];                  // al/ar partials  8 KB

  for (int u = t; u < 640; u += 256) {
    int row = u >> 6, f2 = u & 63;
    const float* xp = x + (size_t)(r0 + row) * F_ + 2 * f2;
    xsh[row * 64 + f2] = pkh2(xp[0], xp[1]);
  }
  if (blockIdx.x == 0 && t < 100)
    ws[AH_OFF + t] = pkh2(avec[2*t], avec[2*t+1]);   // for k_main
  __syncthreads();

  // XJ: pack (x[2jp][f], x[2jp+1][f]) for this block's 5 j-pairs.
  for (int u = t; u < 640; u += 256) {
    int f = u & 127, lp = u >> 7;
    uint32 u0 = xsh[(2*lp)     * 64 + (f >> 1)];
    uint32 u1 = xsh[(2*lp + 1) * 64 + (f >> 1)];
    int sh = (f & 1) * 16;
    ws[XJ_OFF + (size_t)(r0/2 + lp) * 128 + f] =
        ((u0 >> sh) & 0xffffu) | (((u1 >> sh) & 0xffffu) << 16);
  }

  if (t < 200) {
    const bool isR = (t >= 100);
    const int e2 = isR ? (t - 100) : t;          // output uint index within row
    const float* Wp = W + (size_t)(isR ? 128 : 0) * E_ + 2 * e2;

    float acc0[10], acc1[10];
    #pragma unroll
    for (int r = 0; r < 10; ++r) { acc0[r] = 0.f; acc1[r] = 0.f; }

    #pragma unroll
    for (int q = 0; q < 16; ++q) {
      uint32 w0u[4], w1u[4];
      #pragma unroll
      for (int fp = 0; fp < 4; ++fp) {           // per-wave contiguous row reads
        const float* p0 = Wp + (size_t)(8*q + 2*fp) * E_;
        float2 Av = *(const float2*)p0;          // row f  : cols 2e2,2e2+1
        float2 Bv = *(const float2*)(p0 + E_);   // row f+1: cols 2e2,2e2+1
        w0u[fp] = pkh2(Av.x, Bv.x);
        w1u[fp] = pkh2(Av.y, Bv.y);
      }
      #pragma unroll
      for (int r = 0; r < 10; ++r) {
        uint4 xq = *(const uint4*)(xsh + r * 64 + 4 * q);   // uniform -> broadcast
        acc0[r] = FDOT2(bch2(xq.x), bch2(w0u[0]), acc0[r]);
        acc0[r] = FDOT2(bch2(xq.y), bch2(w0u[1]), acc0[r]);
        acc0[r] = FDOT2(bch2(xq.z), bch2(w0u[2]), acc0[r]);
        acc0[r] = FDOT2(bch2(xq.w), bch2(w0u[3]), acc0[r]);
        acc1[r] = FDOT2(bch2(xq.x), bch2(w1u[0]), acc1[r]);
        acc1[r] = FDOT2(bch2(xq.y), bch2(w1u[1]), acc1[r]);
        acc1[r] = FDOT2(bch2(xq.z), bch2(w1u[2]), acc1[r]);
        acc1[r] = FDOT2(bch2(xq.w), bch2(w1u[3]), acc1[r]);
      }
    }
    if (isR) {
      float b0 = bvec[2 * e2], b1 = bvec[2 * e2 + 1];
      #pragma unroll
      for (int r = 0; r < 10; ++r) { acc0[r] += b0; acc1[r] += b1; }
    }
    h2 a2 = bch2(pkh2(avec[2*e2], avec[2*e2+1]));
    uint32* dst = ws + (isR ? RH_OFF : LH_OFF);
    #pragma unroll
    for (int r = 0; r < 10; ++r) {
      uint32 pr = pkh2(acc0[r], acc1[r]);
      dst[(size_t)(r0 + r) * 100 + e2] = pr;
      red[(isR ? 10 : 0) + r][e2] = FDOT2(a2, bch2(pr), 0.f);
    }
  }
  __syncthreads();

  // AL[row] = a · L_row ; AR[row] = a · (R_row + b)
  if (t < 20) {
    float s = 0.f;
    const float* rp = red[t];
    for (int k = 0; k < 100; ++k) s += rp[k];
    float* dstf = (float*)(ws + (t >= 10 ? AR_OFF : AL_OFF));
    dstf[r0 + (t % 10)] = s;
  }
}

// one e-uint (2 e's): nonlinear term only (al/ar hoisted to k_proj)
#define STEP(lu, au, r0u, r1u, r2u, r3u)                                   \
  do {                                                                     \
    h2 a2 = bch2(au); h2 l2 = bch2(lu); h2 mm;                             \
    mm = __builtin_elementwise_min(l2 + bch2(r0u), z2); acc[0] = FDOT2(a2, mm, acc[0]); \
    mm = __builtin_elementwise_min(l2 + bch2(r1u), z2); acc[1] = FDOT2(a2, mm, acc[1]); \
    mm = __builtin_elementwise_min(l2 + bch2(r2u), z2); acc[2] = FDOT2(a2, mm, acc[2]); \
    mm = __builtin_elementwise_min(l2 + bch2(r3u), z2); acc[3] = FDOT2(a2, mm, acc[3]); \
  } while (0)

#define RPAD 104   // 104%32=8 -> max 2-way bank alias (free); %4==0 for uint4
#define LPAD 108   // 108%32=12 -> 2-way max; %4==0

// K2: LDS-staged pair sweep (R3-measured version; offsets renumbered only).
__global__ __launch_bounds__(256) void k_main(
    const float* __restrict__ x, const float* __restrict__ bias,
    const uint32* __restrict__ ws, float* __restrict__ out)
{
  const int t  = threadIdx.x;
  const int i0 = (int)blockIdx.x * 10;
  const int b  = (int)blockIdx.y;

  __shared__ __align__(16) uint32 Rsh[100 * RPAD];  // 41.6 KB
  __shared__ __align__(16) uint32 Lsh[10 * LPAD];   //  4.3 KB
  __shared__ uint32 Ash[100];
  __shared__ float  att[10 * 100];
  __shared__ uint32 att2[10 * 50];
  __shared__ float  scratch[256];
  __shared__ float  rowmax[10], rowinv[10];

  const bool act = (t < 250);
  const int ti = act ? (t % 10) : 0;
  const int tj = act ? (t / 10) : 0;

  // ---- stage R (100 rows), L (10 rows), a into LDS ----
  {
    const uint32* Rb = ws + RH_OFF + (size_t)b * K_ * 100;
    for (int u = t; u < 2500; u += 256) {            // 100 rows x 25 uint4
      int row = u / 25, c4 = (u % 25) * 4;
      *(uint4*)(&Rsh[row * RPAD + c4]) = *(const uint4*)(Rb + (size_t)row * 100 + c4);
    }
    const uint32* Lb = ws + LH_OFF + (size_t)(b * K_ + i0) * 100;
    if (t < 250) {                                   // 10 rows x 25 uint4
      int row = t / 25, c4 = (t % 25) * 4;
      *(uint4*)(&Lsh[row * LPAD + c4]) = *(const uint4*)(Lb + (size_t)row * 100 + c4);
    }
    if (t < 100) Ash[t] = ws[AH_OFF + t];
  }
  __syncthreads();

  float acc[4] = {0.f,0.f,0.f,0.f};
  h2 z2; z2.x = (half_t)0; z2.y = (half_t)0;

  if (act) {
    const uint32* Lp  = Lsh + ti * LPAD;
    const uint32* Rp0 = Rsh + tj * RPAD;
    const uint32* Rp1 = Rsh + (tj + 25) * RPAD;
    const uint32* Rp2 = Rsh + (tj + 50) * RPAD;
    const uint32* Rp3 = Rsh + (tj + 75) * RPAD;
    #pragma unroll 5
    for (int q = 0; q < 25; ++q) {
      uint4 Lq  = *(const uint4*)(Lp  + 4*q);
      uint4 Aq  = *(const uint4*)(Ash + 4*q);
      uint4 R0q = *(const uint4*)(Rp0 + 4*q);
      uint4 R1q = *(const uint4*)(Rp1 + 4*q);
      uint4 R2q = *(const uint4*)(Rp2 + 4*q);
      uint4 R3q = *(const uint4*)(Rp3 + 4*q);
      STEP(Lq.x, Aq.x, R0q.x, R1q.x, R2q.x, R3q.x);
      STEP(Lq.y, Aq.y, R0q.y, R1q.y, R2q.y, R3q.y);
      STEP(Lq.z, Aq.z, R0q.z, R1q.z, R2q.z, R3q.z);
      STEP(Lq.w, Aq.w, R0q.w, R1q.w, R2q.w, R3q.w);
    }
  }

  float v[4];
  if (act) {
    const float* ALf = (const float*)(ws + AL_OFF);
    const float* ARf = (const float*)(ws + AR_OFF);
    float al = ALf[b*K_ + i0 + ti];
    #pragma unroll
    for (int s = 0; s < 4; ++s) {
      int j = tj + 25*s;
      float lv = al + ARf[b*K_ + j] + bias[(i0 + ti)*K_ + j] - 0.8f*acc[s];
      v[s] = fminf(fmaxf(lv, -30000.f), 30000.f);
    }
  }

  {
    float m = -3.0e38f;
    if (act) {
      #pragma unroll
      for (int s = 0; s < 4; ++s) m = fmaxf(m, v[s]);
    }
    scratch[t] = m;
    __syncthreads();
    if (t < 10) {
      float mm = scratch[t];
      for (int k = 1; k < 25; ++k) mm = fmaxf(mm, scratch[t + 10*k]);
      rowmax[t] = mm;
    }
    __syncthreads();
    float ssum = 0.f;
    if (act) {
      float m2 = rowmax[ti];
      #pragma unroll
      for (int s = 0; s < 4; ++s) ssum += __expf(v[s] - m2);
    }
    scratch[t] = ssum;
    __syncthreads();
    if (t < 10) {
      float s2 = 0.f;
      for (int k = 0; k < 25; ++k) s2 += scratch[t + 10*k];
      rowinv[t] = 1.f / s2;
    }
    __syncthreads();
  }
  if (act) {
    float m = rowmax[ti], inv = rowinv[ti];
    #pragma unroll
    for (int s = 0; s < 4; ++s)
      att[ti*K_ + tj + 25*s] = __expf(v[s] - m) * inv;
  }
  __syncthreads();
  for (int u = t; u < 500; u += 256) {
    int i = u / 50, jp = u - i*50;
    att2[i*50 + jp] = pkh2(att[i*K_ + 2*jp], att[i*K_ + 2*jp + 1]);
  }
  __syncthreads();

  {
    const int f = t & 127, ig = t >> 7;        // ig in {0,1}
    const uint32* XJ = ws + XJ_OFF + (size_t)(b*50) * 128;
    float z[5];
    #pragma unroll
    for (int m = 0; m < 5; ++m) z[m] = 0.f;
    for (int jp = 0; jp < 50; ++jp) {
      h2 xv = bch2(XJ[jp*128 + f]);            // coalesced, pre-packed
      #pragma unroll
      for (int m = 0; m < 5; ++m) {
        h2 av = bch2(att2[(ig*5 + m)*50 + jp]);
        z[m] = FDOT2(av, xv, z[m]);
      }
    }
    #pragma unroll
    for (int m = 0; m < 5; ++m) {
      int i = ig*5 + m;
      out[(size_t)(b*K_ + i0 + i)*F_ + f] = 1.f / (1.f + __expf(-z[m]));
    }
  }
}

extern "C" void kernel_launch(void* const* d_in, const int* in_sizes, int n_in,
                              void* d_out, int out_size, void* d_ws, size_t ws_size,
                              hipStream_t stream)
{
  const float* x    = (const float*)d_in[0];   // (64,100,128) f32
  const float* W    = (const float*)d_in[1];   // (256,200) f32
  const float* bvec = (const float*)d_in[2];   // (200,) f32
  const float* avec = (const float*)d_in[3];   // (200,) f32
  const float* bias = (const float*)d_in[4];   // (100,100) f32
  float* out  = (float*)d_out;                 // (64,100,128) f32
  uint32* ws  = (uint32*)d_ws;                 // ~6.8 MB used

  k_proj<<<dim3(640),    dim3(256), 0, stream>>>(x, W, bvec, avec, ws);
  k_main<<<dim3(10, 64), dim3(256), 0, stream>>>(x, bias, ws, out);
}